// Round 2
// 93.837 us; speedup vs baseline: 1.0217x; 1.0217x over previous
//
#include <hip/hip_runtime.h>
#include <math.h>

// Problem constants (fixed by setup_inputs)
#define D     1024   // gd = dn = de
#define N1    48     // n1 = n2
#define E1    192    // e1 = e2
#define NOUT  2304   // n1*n2 = output dim
#define NE    36864  // e1*e2
#define KS    8      // K-split factor (K=128 per block slice)

#define NODE_BLOCKS (9 * KS)                  // 72  (16x16 tiles, 1 out/thread)
#define EDGE_BLOCKS (36 * KS)                 // 288 (32x32 tiles, 2x2 out/thread)
#define AFF_BLOCKS  (NODE_BLOCKS + EDGE_BLOCKS)  // 360
#define ZERO_BLOCKS (NOUT * NOUT / 4096)      // 1296 (4096 floats per block)
#define SCAT_BLOCKS (NE / 256)                // 144
#define DIAG_BLOCKS (NOUT / 256)              // 9

// ---------------------------------------------------------------------------
// K1: coeff = tanh(W @ gw + b); rows [0,1024) node, [1024,2048) edge.
// One block (256 thr) per row: 1024-dot via float4 + wave/LDS reduce.
// ---------------------------------------------------------------------------
__global__ void coeff_kernel(const float* __restrict__ Wn, const float* __restrict__ bn,
                             const float* __restrict__ We, const float* __restrict__ be,
                             const float* __restrict__ gw, float* __restrict__ coeff) {
    int row = blockIdx.x;
    const float* W; const float* b; int d;
    if (row < D) { W = Wn; b = bn; d = row; }
    else         { W = We; b = be; d = row - D; }
    int t = threadIdx.x;
    float4 w = *(const float4*)(W + (size_t)d * D + t * 4);
    float4 g = *(const float4*)(gw + t * 4);
    float s = w.x * g.x + w.y * g.y + w.z * g.z + w.w * g.w;
    #pragma unroll
    for (int off = 32; off > 0; off >>= 1) s += __shfl_down(s, off);
    __shared__ float red[4];
    if ((t & 63) == 0) red[t >> 6] = s;
    __syncthreads();
    if (t == 0) {
        float tot = red[0] + red[1] + red[2] + red[3];
        coeff[row] = tanhf(tot + b[d]);
    }
}

// ---------------------------------------------------------------------------
// K2: fused (a) split-K affinity partials for both matrices and (b) zero-fill
// of the 21 MB output M. Disjoint block ranges -> the pure-write zeroing
// overlaps the read/LDS-bound affinity compute.
//   blocks [0, 72):    node affinity, 16x16 tile, 1 out/thread (proven path)
//   blocks [72, 360):  edge affinity, 32x32 tile, 2x2 micro-tile per thread
//                      (halves LDS-read bytes per FMA: 8 -> 4)
//   blocks [360, 1656): M zeroing, 4096 floats/block, coalesced float4.
// Raw dot partials -> private ks slice: no atomics, no ws zero-init needed.
// ---------------------------------------------------------------------------
__global__ void affinity_zero_kernel(const float* __restrict__ x1, const float* __restrict__ x2,
                                     const float* __restrict__ ef1, const float* __restrict__ ef2,
                                     const float* __restrict__ coeff,
                                     float* __restrict__ Mp_part, float* __restrict__ Me_part,
                                     float* __restrict__ M) {
    __shared__ float As[32][68];
    __shared__ float Bs[32][68];
    int bid = blockIdx.x;
    int t = threadIdx.x;

    if (bid >= AFF_BLOCKS) {
        // ---- zero-fill branch: block covers 4096 consecutive floats of M
        size_t base = (size_t)(bid - AFF_BLOCKS) * 4096 + t * 4;
        float4 z = make_float4(0.f, 0.f, 0.f, 0.f);
        #pragma unroll
        for (int p = 0; p < 4; p++)
            *(float4*)(M + base + p * 1024) = z;
        return;
    }

    if (bid < NODE_BLOCKS) {
        // ---- node path: 16x16 tile over x1/x2 (proven code)
        int tile = bid >> 3, ks = bid & 7;
        int ty = tile / 3, tx = tile - ty * 3;
        int r  = t >> 4;          // 0..15: tile row (load + compute)
        int cb = (t & 15) << 2;   // 0..60: k-column base for loads
        int cc = t & 15;          // 0..15: tile col (compute)
        size_t rowA = (size_t)(ty * 16 + r);
        size_t rowB = (size_t)(tx * 16 + r);
        float acc = 0.f;
        #pragma unroll
        for (int ch = 0; ch < 2; ch++) {
            int k0 = ks * 128 + ch * 64;
            float4 a = *(const float4*)(x1 + rowA * D + k0 + cb);
            float4 c = *(const float4*)(coeff + k0 + cb);
            float4 b = *(const float4*)(x2 + rowB * D + k0 + cb);
            *(float4*)&As[r][cb] = make_float4(a.x * c.x, a.y * c.y, a.z * c.z, a.w * c.w);
            *(float4*)&Bs[r][cb] = b;
            __syncthreads();
            #pragma unroll
            for (int kk = 0; kk < 64; kk += 4) {
                float4 av = *(const float4*)&As[r][kk];
                float4 bv = *(const float4*)&Bs[cc][kk];
                acc = fmaf(av.x, bv.x, acc);
                acc = fmaf(av.y, bv.y, acc);
                acc = fmaf(av.z, bv.z, acc);
                acc = fmaf(av.w, bv.w, acc);
            }
            __syncthreads();
        }
        Mp_part[ks * NOUT + (size_t)(ty * 16 + r) * N1 + tx * 16 + cc] = acc;
        return;
    }

    // ---- edge path: 32x32 tile, 2x2 micro-tile, split-K 8
    {
        int b = bid - NODE_BLOCKS;
        int tile = b >> 3, ks = b & 7;
        int ty = tile / 6, tx = tile - ty * 6;
        int a0 = ty * 32, b0 = tx * 32;
        const float* cf = coeff + D;

        int i  = t >> 4;          // 0..15: compute row pair (i, i+16)
        int j  = t & 15;          // 0..15: compute col pair (j, j+16)
        int lr = t >> 3;          // 0..31: load row
        int lc = (t & 7) << 3;    // 0..56: load col base (8 floats/thread)

        float acc00 = 0.f, acc01 = 0.f, acc10 = 0.f, acc11 = 0.f;
        #pragma unroll
        for (int ch = 0; ch < 2; ch++) {
            int k0 = ks * 128 + ch * 64;
            const float* Ap = ef1 + (size_t)(a0 + lr) * D + k0 + lc;
            const float* Bp = ef2 + (size_t)(b0 + lr) * D + k0 + lc;
            float4 a1 = *(const float4*)(Ap);
            float4 a2 = *(const float4*)(Ap + 4);
            float4 c1 = *(const float4*)(cf + k0 + lc);
            float4 c2 = *(const float4*)(cf + k0 + lc + 4);
            float4 b1 = *(const float4*)(Bp);
            float4 b2 = *(const float4*)(Bp + 4);
            *(float4*)&As[lr][lc]     = make_float4(a1.x * c1.x, a1.y * c1.y, a1.z * c1.z, a1.w * c1.w);
            *(float4*)&As[lr][lc + 4] = make_float4(a2.x * c2.x, a2.y * c2.y, a2.z * c2.z, a2.w * c2.w);
            *(float4*)&Bs[lr][lc]     = b1;
            *(float4*)&Bs[lr][lc + 4] = b2;
            __syncthreads();
            #pragma unroll
            for (int kk = 0; kk < 64; kk += 4) {
                float4 aA = *(const float4*)&As[i][kk];
                float4 aB = *(const float4*)&As[i + 16][kk];
                float4 bA = *(const float4*)&Bs[j][kk];
                float4 bB = *(const float4*)&Bs[j + 16][kk];
                acc00 = fmaf(aA.x, bA.x, acc00); acc00 = fmaf(aA.y, bA.y, acc00);
                acc00 = fmaf(aA.z, bA.z, acc00); acc00 = fmaf(aA.w, bA.w, acc00);
                acc01 = fmaf(aA.x, bB.x, acc01); acc01 = fmaf(aA.y, bB.y, acc01);
                acc01 = fmaf(aA.z, bB.z, acc01); acc01 = fmaf(aA.w, bB.w, acc01);
                acc10 = fmaf(aB.x, bA.x, acc10); acc10 = fmaf(aB.y, bA.y, acc10);
                acc10 = fmaf(aB.z, bA.z, acc10); acc10 = fmaf(aB.w, bA.w, acc10);
                acc11 = fmaf(aB.x, bB.x, acc11); acc11 = fmaf(aB.y, bB.y, acc11);
                acc11 = fmaf(aB.z, bB.z, acc11); acc11 = fmaf(aB.w, bB.w, acc11);
            }
            __syncthreads();
        }
        float* out = Me_part + ks * NE;
        int ra = a0 + i, rb = ra + 16;
        int ca = b0 + j, cb2 = ca + 16;
        out[(size_t)ra * E1 + ca]  = acc00;
        out[(size_t)ra * E1 + cb2] = acc01;
        out[(size_t)rb * E1 + ca]  = acc10;
        out[(size_t)rb * E1 + cb2] = acc11;
    }
}

__device__ __forceinline__ float act(float x) {
    float sp = fmaxf(x, 0.f) + log1pf(expf(-fabsf(x)));   // stable softplus
    return fmaxf(sp - 0.5f, 0.f);
}

// ---------------------------------------------------------------------------
// K3: fused scatter + diagonal. All additions via atomicAdd onto the zeroed M
// (order-independent, so diag and scatter can share one launch even when a
// self-loop edge pair lands on the diagonal).
// ---------------------------------------------------------------------------
__global__ void scatter_diag_kernel(float* __restrict__ M,
                                    const float* __restrict__ Mp_part,
                                    const float* __restrict__ Me_part,
                                    const int* __restrict__ ei1, const int* __restrict__ ei2) {
    int bid = blockIdx.x;
    int t = threadIdx.x;
    if (bid < SCAT_BLOCKS) {
        int q = bid * 256 + t;
        float s = 0.f;
        #pragma unroll
        for (int ks = 0; ks < KS; ks++) s += Me_part[ks * NE + q];
        float v = act(s);
        if (v > 0.f) {
            int b2 = q / E1;
            int b1 = q - b2 * E1;
            int r = ei2[b2]      * N1 + ei1[b1];
            int c = ei2[E1 + b2] * N1 + ei1[E1 + b1];
            atomicAdd(M + (size_t)r * NOUT + c, v);
        }
    } else {
        int r = (bid - SCAT_BLOCKS) * 256 + t;
        float s = 0.f;
        #pragma unroll
        for (int ks = 0; ks < KS; ks++) s += Mp_part[ks * NOUT + r];
        float v = act(s);
        if (v > 0.f) atomicAdd(M + (size_t)r * NOUT + r, v);
    }
}

extern "C" void kernel_launch(void* const* d_in, const int* in_sizes, int n_in,
                              void* d_out, int out_size, void* d_ws, size_t ws_size,
                              hipStream_t stream) {
    const float* x1  = (const float*)d_in[0];
    const float* x2  = (const float*)d_in[1];
    const float* ef1 = (const float*)d_in[2];
    const float* ef2 = (const float*)d_in[3];
    const float* gw  = (const float*)d_in[4];
    const float* Wn  = (const float*)d_in[5];
    const float* bn  = (const float*)d_in[6];
    const float* We  = (const float*)d_in[7];
    const float* be  = (const float*)d_in[8];
    const int*   ei1 = (const int*)d_in[9];
    const int*   ei2 = (const int*)d_in[10];

    float* M  = (float*)d_out;
    float* ws = (float*)d_ws;
    float* coeff   = ws;                         // 2048 floats
    float* Mp_part = ws + 2048;                  // KS * 2304
    float* Me_part = Mp_part + KS * NOUT;        // KS * 36864

    coeff_kernel<<<2 * D, 256, 0, stream>>>(Wn, bn, We, be, gw, coeff);
    affinity_zero_kernel<<<AFF_BLOCKS + ZERO_BLOCKS, 256, 0, stream>>>(
        x1, x2, ef1, ef2, coeff, Mp_part, Me_part, M);
    scatter_diag_kernel<<<SCAT_BLOCKS + DIAG_BLOCKS, 256, 0, stream>>>(
        M, Mp_part, Me_part, ei1, ei2);
}